// Round 6
// baseline (333.667 us; speedup 1.0000x reference)
//
#include <hip/hip_runtime.h>
#include <math.h>

typedef short s8 __attribute__((ext_vector_type(8)));   // 8 bf16 in 4 VGPRs
typedef float f4 __attribute__((ext_vector_type(4)));   // MFMA 16x16 acc
typedef unsigned short ushort_t;

__device__ __forceinline__ float fexp2f(float x) { return __builtin_amdgcn_exp2f(x); }
__device__ __forceinline__ float frcpf(float x)  { return __builtin_amdgcn_rcpf(x); }
__device__ __forceinline__ float sigf(float x) {
    return frcpf(1.f + fexp2f(x * -1.44269504f));
}
__device__ __forceinline__ float tanh_f(float x) {
    float e = fexp2f(x * 2.88539008f);
    return 1.f - 2.f * frcpf(e + 1.f);
}
__device__ __forceinline__ ushort_t f2b(float f) {
    unsigned u = __float_as_uint(f);
    u = (u + 0x7FFF + ((u >> 16) & 1)) >> 16;   // RNE
    return (ushort_t)u;
}
__device__ __forceinline__ float b2f(ushort_t b) {
    return __uint_as_float(((unsigned)b) << 16);
}

// ---------------------------------------------------------------------------
// Convert emb / Wih / Whh / SW^T to bf16, 4 elems/thread.
// ---------------------------------------------------------------------------
#define EMB_N   6400000          // 50000*128
#define W_N     49152            // 384*128
#define SW_N    16384            // 128*128
#define CVT_N   (EMB_N + 2 * W_N + SW_N)

__global__ __launch_bounds__(256) void cvt_kernel(
    const float* __restrict__ emb, const float* __restrict__ wih,
    const float* __restrict__ whh, const float* __restrict__ sw,
    ushort_t* __restrict__ embb, ushort_t* __restrict__ wihb,
    ushort_t* __restrict__ whhb, ushort_t* __restrict__ swtb)
{
    int i = (blockIdx.x * 256 + threadIdx.x) * 4;
    if (i >= CVT_N) return;
    if (i < EMB_N) {
        float4 v = *(const float4*)(emb + i);
        short4 o; o.x = f2b(v.x); o.y = f2b(v.y); o.z = f2b(v.z); o.w = f2b(v.w);
        *(short4*)(embb + i) = o;
    } else if (i < EMB_N + W_N) {
        int j = i - EMB_N;
        float4 v = *(const float4*)(wih + j);
        short4 o; o.x = f2b(v.x); o.y = f2b(v.y); o.z = f2b(v.z); o.w = f2b(v.w);
        *(short4*)(wihb + j) = o;
    } else if (i < EMB_N + 2 * W_N) {
        int j = i - EMB_N - W_N;
        float4 v = *(const float4*)(whh + j);
        short4 o; o.x = f2b(v.x); o.y = f2b(v.y); o.z = f2b(v.z); o.w = f2b(v.w);
        *(short4*)(whhb + j) = o;
    } else {
        int j = i - EMB_N - 2 * W_N;
        int f = j >> 7, e0 = j & 127;
        short4 o;
        o.x = f2b(sw[(e0 + 0) * 128 + f]);
        o.y = f2b(sw[(e0 + 1) * 128 + f]);
        o.z = f2b(sw[(e0 + 2) * 128 + f]);
        o.w = f2b(sw[(e0 + 3) * 128 + f]);
        *(short4*)(swtb + j) = o;        // SWt[f][e]
    }
}

// ---------------------------------------------------------------------------
// Fused level kernel: GRU (child level) -> [h in LDS] -> sibling-max (bf16
// pmax partial) + child attention -> parent h0. h NEVER goes to HBM.
//
// MODE 0: leaf (no h0 in) + attn; MODE 1: internal + attn; MODE 2: root
// (h0 in, no attn; h rows written straight to the root pmax slot).
//
// Block = 512 thr (8 waves), 64 child rows = 4 sibling nodes x 16 batch
// (k-major: lr = k*16 + bl), parent p = blockIdx.x>>4, y = blockIdx.x&15.
// GRU: wave w owns gate-cols w*16..+15; operand-swapped MFMA so a lane's
// 4 acc regs are 4 consecutive cols of one row; per-mt __syncthreads then
// h overwrites the (dead) xs tile. Attention afterwards reads h from xs.
// ---------------------------------------------------------------------------
template <int MODE>
__global__ __launch_bounds__(512, 2) void level_kernel(
    const int* __restrict__ tokens, const ushort_t* __restrict__ embb,
    const ushort_t* __restrict__ wihb, const ushort_t* __restrict__ whhb,
    const float* __restrict__ bih, const float* __restrict__ bhh,
    const ushort_t* __restrict__ swtb, const float* __restrict__ sbv,
    const float* __restrict__ cwv,
    const ushort_t* __restrict__ h0in, ushort_t* __restrict__ h0out,
    ushort_t* __restrict__ pmaxs, int tok_start)
{
    constexpr bool H0 = (MODE != 0);
    constexpr bool ATTN = (MODE != 2);

    __shared__ ushort_t xs[64 * 136];               // x, then h (bf16)
    __shared__ ushort_t hs[H0 ? 64 * 136 : 8];      // h0 of child rows
    __shared__ float scp[8][64];
    __shared__ float sc[64];
    __shared__ float al[4][16];

    const int t = threadIdx.x;
    const int p = ATTN ? (int)(blockIdx.x >> 4) : 0;
    const int y = ATTN ? (int)(blockIdx.x & 15) : (int)blockIdx.x;

    // ---- stage x (emb gather) and h0: 8 threads/row, 16 shorts each ----
    {
        int lr = t >> 3, ci = (t & 7) * 16;
        int node, b;
        if (ATTN) { node = 4 * p + (lr >> 4); b = y * 16 + (lr & 15); }
        else      { node = 0;                 b = y * 64 + lr; }
        int tok = tokens[(tok_start + node) * 256 + b];
        const ushort_t* src = embb + (size_t)tok * 128 + ci;
        ushort_t* dst = &xs[lr * 136 + ci];
        *(s8*)dst       = *(const s8*)src;
        *(s8*)(dst + 8) = *(const s8*)(src + 8);
        if (H0) {
            const ushort_t* hsrc = h0in + ((size_t)node * 256 + b) * 128 + ci;
            ushort_t* hdst = &hs[lr * 136 + ci];
            *(s8*)hdst       = *(const s8*)hsrc;
            *(s8*)(hdst + 8) = *(const s8*)(hsrc + 8);
        }
    }

    const int lane = t & 63, w = t >> 6;
    const int quad = lane >> 4, l15 = lane & 15;
    const int gA = w * 16 + l15;          // gate col this lane supplies (A op)
    const int g0 = w * 16 + quad * 4;     // epilogue col group (D m-index)

    // ---- weights ----
    s8 bwi[3][4], bwh[3][4];
    #pragma unroll
    for (int gm = 0; gm < 3; ++gm) {
        const ushort_t* wp = wihb + (size_t)(gm * 128 + gA) * 128 + quad * 8;
        #pragma unroll
        for (int s = 0; s < 4; ++s) bwi[gm][s] = *(const s8*)(wp + 32 * s);
    }
    if (H0) {
        #pragma unroll
        for (int gm = 0; gm < 3; ++gm) {
            const ushort_t* wp = whhb + (size_t)(gm * 128 + gA) * 128 + quad * 8;
            #pragma unroll
            for (int s = 0; s < 4; ++s) bwh[gm][s] = *(const s8*)(wp + 32 * s);
        }
    }

    // ---- biases folded into acc init ----
    f4 cR0, cZ0, cN0, cNh0;
    float bhN4[4];
    {
        float4 a = *(const float4*)(bih + g0);
        float4 b = *(const float4*)(bhh + g0);
        cR0[0] = a.x + b.x; cR0[1] = a.y + b.y; cR0[2] = a.z + b.z; cR0[3] = a.w + b.w;
        float4 c = *(const float4*)(bih + 128 + g0);
        float4 d = *(const float4*)(bhh + 128 + g0);
        cZ0[0] = c.x + d.x; cZ0[1] = c.y + d.y; cZ0[2] = c.z + d.z; cZ0[3] = c.w + d.w;
        float4 e = *(const float4*)(bih + 256 + g0);
        float4 f = *(const float4*)(bhh + 256 + g0);
        cN0[0] = e.x; cN0[1] = e.y; cN0[2] = e.z; cN0[3] = e.w;
        bhN4[0] = f.x; bhN4[1] = f.y; bhN4[2] = f.z; bhN4[3] = f.w;
        cNh0[0] = f.x; cNh0[1] = f.y; cNh0[2] = f.z; cNh0[3] = f.w;
    }

    __syncthreads();

    // ---- GRU: 4 M-tiles of 16 rows; h overwrites xs tile after barrier ----
    #pragma unroll 1
    for (int mt = 0; mt < 4; ++mt) {
        const int row = mt * 16 + l15;
        s8 ax[4], ah[4];
        {
            const ushort_t* ap = &xs[row * 136 + quad * 8];
            #pragma unroll
            for (int s = 0; s < 4; ++s) ax[s] = *(const s8*)(ap + 32 * s);
            if (H0) {
                const ushort_t* hp = &hs[row * 136 + quad * 8];
                #pragma unroll
                for (int s = 0; s < 4; ++s) ah[s] = *(const s8*)(hp + 32 * s);
            }
        }

        f4 accR = cR0, accZ = cZ0, accN = cN0, accNh = cNh0;
        #pragma unroll
        for (int s = 0; s < 4; ++s) {
            accR = __builtin_amdgcn_mfma_f32_16x16x32_bf16(bwi[0][s], ax[s], accR, 0, 0, 0);
            accZ = __builtin_amdgcn_mfma_f32_16x16x32_bf16(bwi[1][s], ax[s], accZ, 0, 0, 0);
            accN = __builtin_amdgcn_mfma_f32_16x16x32_bf16(bwi[2][s], ax[s], accN, 0, 0, 0);
        }
        if (H0) {
            #pragma unroll
            for (int s = 0; s < 4; ++s) {
                accR  = __builtin_amdgcn_mfma_f32_16x16x32_bf16(bwh[0][s], ah[s], accR, 0, 0, 0);
                accZ  = __builtin_amdgcn_mfma_f32_16x16x32_bf16(bwh[1][s], ah[s], accZ, 0, 0, 0);
                accNh = __builtin_amdgcn_mfma_f32_16x16x32_bf16(bwh[2][s], ah[s], accNh, 0, 0, 0);
            }
        }

        __syncthreads();   // all reads of tile mt done -> safe to overwrite xs

        float h0v[4] = {0.f, 0.f, 0.f, 0.f};
        if (H0) {
            short4 h04 = *(const short4*)&hs[row * 136 + g0];
            h0v[0] = b2f((ushort_t)h04.x); h0v[1] = b2f((ushort_t)h04.y);
            h0v[2] = b2f((ushort_t)h04.z); h0v[3] = b2f((ushort_t)h04.w);
        }
        ushort_t ov[4];
        #pragma unroll
        for (int r = 0; r < 4; ++r) {
            float rr = sigf(accR[r]);
            float zz = sigf(accZ[r]);
            float hn = H0 ? accNh[r] : bhN4[r];
            float nn = tanh_f(accN[r] + rr * hn);
            float h = nn + zz * (h0v[r] - nn);
            ov[r] = f2b(h);
        }
        *(short4*)&xs[row * 136 + g0] = *(const short4*)ov;
    }
    __syncthreads();   // h fully materialized in xs

    if (MODE == 2) {
        // root: write h rows straight to root pmax slot (bf16)
        int row = t >> 3, ci = (t & 7) * 16;
        ushort_t* d = pmaxs + ((size_t)(y * 64 + row)) * 128 + ci;
        const ushort_t* s_ = &xs[row * 136 + ci];
        *(s8*)d       = *(const s8*)s_;
        *(s8*)(d + 8) = *(const s8*)(s_ + 8);
        return;
    }

    // ---- attention over the 4 siblings (u never materialized) ----
    s8 bsw[4];
    {
        const ushort_t* wp = swtb + (size_t)gA * 128 + quad * 8;
        #pragma unroll
        for (int s = 0; s < 4; ++s) bsw[s] = *(const s8*)(wp + 32 * s);
    }
    f4 sb0;
    float cw4[4];
    {
        float4 a = *(const float4*)(sbv + g0);
        sb0[0] = a.x; sb0[1] = a.y; sb0[2] = a.z; sb0[3] = a.w;
        float4 b = *(const float4*)(cwv + g0);
        cw4[0] = b.x; cw4[1] = b.y; cw4[2] = b.z; cw4[3] = b.w;
    }

    #pragma unroll 1
    for (int mt = 0; mt < 4; ++mt) {
        const int crow = mt * 16 + l15;
        s8 a[4];
        const ushort_t* ap = &xs[crow * 136 + quad * 8];
        #pragma unroll
        for (int s = 0; s < 4; ++s) a[s] = *(const s8*)(ap + 32 * s);

        f4 acc = sb0;
        #pragma unroll
        for (int s = 0; s < 4; ++s)
            acc = __builtin_amdgcn_mfma_f32_16x16x32_bf16(bsw[s], a[s], acc, 0, 0, 0);

        float part = 0.f;
        #pragma unroll
        for (int r = 0; r < 4; ++r)
            part += tanh_f(acc[r]) * cw4[r];
        part += __shfl_xor(part, 16);
        part += __shfl_xor(part, 32);
        if (quad == 0) scp[w][crow] = part;
    }
    __syncthreads();

    if (t < 64) {
        float s_ = 0.f;
        #pragma unroll
        for (int ww = 0; ww < 8; ++ww) s_ += scp[ww][t];
        sc[t] = tanh_f(s_);
    }
    __syncthreads();

    if (t < 16) {
        float s0 = sc[t], s1 = sc[16 + t], s2 = sc[32 + t], s3 = sc[48 + t];
        float m = fmaxf(fmaxf(s0, s1), fmaxf(s2, s3));
        float e0 = fexp2f((s0 - m) * 1.44269504f), e1 = fexp2f((s1 - m) * 1.44269504f);
        float e2 = fexp2f((s2 - m) * 1.44269504f), e3 = fexp2f((s3 - m) * 1.44269504f);
        float inv = frcpf(e0 + e1 + e2 + e3);
        al[0][t] = e0 * inv; al[1][t] = e1 * inv; al[2][t] = e2 * inv; al[3][t] = e3 * inv;
    }
    __syncthreads();

    if (t < 256) {
        // h0 epilogue: 16 parent rows x 128 e
        int bl = t >> 4, e0 = (t & 15) * 8;
        float a0 = al[0][bl], a1 = al[1][bl], a2 = al[2][bl], a3 = al[3][bl];
        s8 c0 = *(const s8*)&xs[(0 * 16 + bl) * 136 + e0];
        s8 c1 = *(const s8*)&xs[(1 * 16 + bl) * 136 + e0];
        s8 c2 = *(const s8*)&xs[(2 * 16 + bl) * 136 + e0];
        s8 c3 = *(const s8*)&xs[(3 * 16 + bl) * 136 + e0];
        ushort_t ov[8];
        #pragma unroll
        for (int j = 0; j < 8; ++j) {
            float v = a0 * b2f((ushort_t)c0[j]) + a1 * b2f((ushort_t)c1[j])
                    + a2 * b2f((ushort_t)c2[j]) + a3 * b2f((ushort_t)c3[j]);
            ov[j] = f2b(v);
        }
        *(s8*)(h0out + ((size_t)p * 256 + y * 16 + bl) * 128 + e0) = *(const s8*)ov;
    } else {
        // sibling max -> bf16 pmax partial
        int tt = t - 256;
        int bl = tt >> 4, e0 = (tt & 15) * 8;
        s8 c0 = *(const s8*)&xs[(0 * 16 + bl) * 136 + e0];
        s8 c1 = *(const s8*)&xs[(1 * 16 + bl) * 136 + e0];
        s8 c2 = *(const s8*)&xs[(2 * 16 + bl) * 136 + e0];
        s8 c3 = *(const s8*)&xs[(3 * 16 + bl) * 136 + e0];
        ushort_t ov[8];
        #pragma unroll
        for (int j = 0; j < 8; ++j) {
            float v = fmaxf(fmaxf(b2f((ushort_t)c0[j]), b2f((ushort_t)c1[j])),
                            fmaxf(b2f((ushort_t)c2[j]), b2f((ushort_t)c3[j])));
            ov[j] = f2b(v);   // exact: max of bf16 values re-rounds to itself
        }
        *(s8*)(pmaxs + (size_t)p * 32768 + (size_t)(y * 16 + bl) * 128 + e0) = *(const s8*)ov;
    }
}

// ---------------------------------------------------------------------------
// Final: out[b*128+e] = max over 342 bf16 pmax slots (256+64+16+4+1+root).
// ---------------------------------------------------------------------------
#define N_SLOTS 342
__global__ __launch_bounds__(256) void final_max(
    const ushort_t* __restrict__ pmax, float* __restrict__ out)
{
    int i = blockIdx.x * 256 + threadIdx.x;   // 0..4095
    int e0 = i * 8;
    float v[8];
    {
        s8 c = *(const s8*)(pmax + e0);
        #pragma unroll
        for (int j = 0; j < 8; ++j) v[j] = b2f((ushort_t)c[j]);
    }
    #pragma unroll 4
    for (int s_ = 1; s_ < N_SLOTS; ++s_) {
        s8 c = *(const s8*)(pmax + (size_t)s_ * 32768 + e0);
        #pragma unroll
        for (int j = 0; j < 8; ++j) v[j] = fmaxf(v[j], b2f((ushort_t)c[j]));
    }
    float4 o0 = make_float4(v[0], v[1], v[2], v[3]);
    float4 o1 = make_float4(v[4], v[5], v[6], v[7]);
    *(float4*)(out + e0)     = o0;
    *(float4*)(out + e0 + 4) = o1;
}

extern "C" void kernel_launch(void* const* d_in, const int* in_sizes, int n_in,
                              void* d_out, int out_size, void* d_ws, size_t ws_size,
                              hipStream_t stream)
{
    const int*   tokens = (const int*)d_in[0];
    const float* emb    = (const float*)d_in[1];
    const float* Wih    = (const float*)d_in[2];
    const float* Whh    = (const float*)d_in[3];
    const float* bih    = (const float*)d_in[4];
    const float* bhh    = (const float*)d_in[5];
    const float* SW     = (const float*)d_in[6];
    const float* sb     = (const float*)d_in[7];
    const float* cw     = (const float*)d_in[8];
    float* out = (float*)d_out;

    // ws: emb 12.8MB | W 0.26MB | h0A 16.8MB | h0B 16.8MB | pmax 22.4MB
    ushort_t* embb = (ushort_t*)d_ws;
    ushort_t* wihb = embb + (size_t)EMB_N;
    ushort_t* whhb = wihb + W_N;
    ushort_t* swtb = whhb + W_N;
    ushort_t* h0A  = swtb + SW_N;
    ushort_t* h0B  = h0A + (size_t)65536 * 128;
    ushort_t* pmax = h0B + (size_t)65536 * 128;
    // pmax slot offsets (each slot = 256*128 bf16 = 32768 shorts):
    // L5: 0..255 | L4: 256..319 | L3: 320..335 | L2: 336..339 | L1: 340 | root: 341

    cvt_kernel<<<(CVT_N / 4 + 255) / 256, 256, 0, stream>>>(
        emb, Wih, Whh, SW, embb, wihb, whhb, swtb);

    // L5: leaf GRU + attn -> h0(level4) ; token start 341 ; 256 parents
    level_kernel<0><<<4096, 512, 0, stream>>>(
        tokens, embb, wihb, whhb, bih, bhh, swtb, sb, cw,
        nullptr, h0A, pmax + (size_t)0 * 32768, 341);
    // L4: level-4 GRU + attn -> h0(level3) ; 64 parents
    level_kernel<1><<<1024, 512, 0, stream>>>(
        tokens, embb, wihb, whhb, bih, bhh, swtb, sb, cw,
        h0A, h0B, pmax + (size_t)256 * 32768, 85);
    // L3: 16 parents
    level_kernel<1><<<256, 512, 0, stream>>>(
        tokens, embb, wihb, whhb, bih, bhh, swtb, sb, cw,
        h0B, h0A, pmax + (size_t)320 * 32768, 21);
    // L2: 4 parents
    level_kernel<1><<<64, 512, 0, stream>>>(
        tokens, embb, wihb, whhb, bih, bhh, swtb, sb, cw,
        h0A, h0B, pmax + (size_t)336 * 32768, 5);
    // L1: 1 parent (root h0)
    level_kernel<1><<<16, 512, 0, stream>>>(
        tokens, embb, wihb, whhb, bih, bhh, swtb, sb, cw,
        h0B, h0A, pmax + (size_t)340 * 32768, 1);
    // root: GRU only, h -> root pmax slot
    level_kernel<2><<<4, 512, 0, stream>>>(
        tokens, embb, wihb, whhb, bih, bhh, swtb, sb, cw,
        h0A, nullptr, pmax + (size_t)341 * 32768, 0);

    final_max<<<16, 256, 0, stream>>>(pmax, out);
}